// Round 3
// baseline (427.816 us; speedup 1.0000x reference)
//
#include <hip/hip_runtime.h>
#include <hip/hip_bf16.h>
#include <stdint.h>

typedef __attribute__((ext_vector_type(8))) __bf16 bf16x8;
typedef __attribute__((ext_vector_type(4))) float floatx4;

#define EPS 1e-5f

__device__ __forceinline__ unsigned short f2bf(float f) {
    union { float f; unsigned int u; } x; x.f = f;
    unsigned int r = x.u + 0x7fffu + ((x.u >> 16) & 1u);
    return (unsigned short)(r >> 16);
}

__device__ __forceinline__ float bf2f(unsigned int u) {
    union { unsigned int u; float f; } x; x.u = u << 16; return x.f;
}

struct Params2 {
    const float* x_in;
    const int*   knn;
    const float* w1s[3];   // [128][512]
    const float* w2s[3];   // [512][128]
    const float* vws[2];   // [128][128]
    unsigned short* W1P[3];
    unsigned short* W2P[3];
    unsigned short* VTP[2];
    const float* b1s[3];
    const float* b2s[3];
    const float* gs[3];
    const float* bes[3];
    const float* ms[3];
    const float* vvs[3];
    const float* vbb[2];
    const float* vgg[2];
    const float* vbt[2];
    const float* vmm[2];
    const float* vva[2];
    unsigned short* Vb0;
    unsigned short* Vb1;
    unsigned int*   ctr;
    float* xf;
};

// ---------------- pack weights, DEST-major (coalesced uint4 stores) --------
// Fragment layout (consumer side, unchanged):
// W1P short-addr d = hf*16384 + w*2048 + ks*512 + q*128 + ln*8 + j
//   holds W1[k=32ks+8q+j][h=128hf+16w+ln]   (src [128][512], idx=k*512+h)
// W2P same d-layout, holds W2[h=128hf+32ks+8q+j][c=16w+ln]  (src idx=h*128+c)
// VTP d = w*2048+ks*512+q*128+ln*8+j, holds Wv[k=32ks+8q+j][c=16w+ln]
// One thread per 8-short fragment -> 16B uint4 store, coalesced.
// Also zeroes the per-batch barrier counters (ctr[0..15]) each run.
__global__ __launch_bounds__(256) void pack2(Params2 P) {
    const int gtid = blockIdx.x * 256 + threadIdx.x;
    unsigned short v[8];
    if (gtid < 24576) {                       // W1 x3: 3*8192 fragments
        const int t = gtid >> 13;
        const int d = (gtid & 8191) << 3;
        const int hf = d >> 14, w = (d >> 11) & 7, ks = (d >> 9) & 3,
                  q = (d >> 7) & 3, ln = (d >> 3) & 15;
        const float* s1 = P.w1s[t];
        const int hcol = 128 * hf + 16 * w + ln;
        const int kb   = 32 * ks + 8 * q;
#pragma unroll
        for (int j = 0; j < 8; ++j) v[j] = f2bf(s1[(kb + j) * 512 + hcol]);
        uint4 pk;
        pk.x = v[0] | ((unsigned)v[1] << 16); pk.y = v[2] | ((unsigned)v[3] << 16);
        pk.z = v[4] | ((unsigned)v[5] << 16); pk.w = v[6] | ((unsigned)v[7] << 16);
        *(uint4*)&P.W1P[t][d] = pk;
    } else if (gtid < 49152) {                // W2 x3: 3*8192 fragments
        const int g = gtid - 24576;
        const int t = g >> 13;
        const int d = (g & 8191) << 3;
        const int hf = d >> 14, w = (d >> 11) & 7, ks = (d >> 9) & 3,
                  q = (d >> 7) & 3, ln = (d >> 3) & 15;
        const float* s2 = P.w2s[t];
        const int col = 16 * w + ln;
        const int hb  = 128 * hf + 32 * ks + 8 * q;
#pragma unroll
        for (int j = 0; j < 8; ++j) v[j] = f2bf(s2[(hb + j) * 128 + col]);
        uint4 pk;
        pk.x = v[0] | ((unsigned)v[1] << 16); pk.y = v[2] | ((unsigned)v[3] << 16);
        pk.z = v[4] | ((unsigned)v[5] << 16); pk.w = v[6] | ((unsigned)v[7] << 16);
        *(uint4*)&P.W2P[t][d] = pk;
    } else if (gtid < 53248) {                // VT x2: 2*2048 fragments
        const int g = gtid - 49152;
        const int t = g >> 11;
        const int d = (g & 2047) << 3;
        const int w = (d >> 11) & 7, ks = (d >> 9) & 3,
                  q = (d >> 7) & 3, ln = (d >> 3) & 15;
        const float* sv = P.vws[t];
        const int col = 16 * w + ln;
        const int kb  = 32 * ks + 8 * q;
#pragma unroll
        for (int j = 0; j < 8; ++j) v[j] = f2bf(sv[(kb + j) * 128 + col]);
        uint4 pk;
        pk.x = v[0] | ((unsigned)v[1] << 16); pk.y = v[2] | ((unsigned)v[3] << 16);
        pk.z = v[4] | ((unsigned)v[5] << 16); pk.w = v[6] | ((unsigned)v[7] << 16);
        *(uint4*)&P.VTP[t][d] = pk;
    } else if (gtid < 53264) {
        P.ctr[gtid - 53248] = 0;              // barrier counters, re-init each run
    }
}

// ---------------- fully fused kernel (plain launch, capacity-resident) -----
// 512 blocks x 512 thr (8 waves), 80 KB LDS, __launch_bounds__(512,4)
// => <=128 VGPR, exactly 2 blocks/CU, grid == 2 x 256 CU: ALL blocks
// resident at dispatch (capacity co-residency; no cooperative launch —
// coop is incompatible with the harness's graph capture, which is why R2
// silently produced zeros). Each block owns 64 points for the whole
// network; x stays resident in LDS (xf32/xt) across all 3 logical stages.
// Only cross-block dependency is the KNN gather (batch-local); two
// per-batch 64-block spin barriers (monotonic counter, release/acquire
// agent scope -> compiler emits cross-XCD L2 wb/inv) replace kernel
// launches. Spin is bounded (~0.4s) so a violated residency assumption
// fails cleanly instead of hanging.
__global__ __launch_bounds__(512, 4)
void fused(Params2 P)
{
    __shared__ __align__(16) unsigned short xt[8192];   // 16 KB bf16 x tile
    __shared__ __align__(16) float xf32[8192];          // 32 KB fp32 x tile
    __shared__ __align__(16) uint2 ht2[2][2048];        // 32 KB h banks
    const int tid  = threadIdx.x;
    const int lane = tid & 63;
    const int w    = tid >> 6;       // wave 0..7
    const int q    = lane >> 4;
    const int ln   = lane & 15;
    const int sw   = ln & 7;
    const int phys = blockIdx.x;
    const int bid  = (phys & 7) * 64 + (phys >> 3);   // XCD-local batches
    const int p0   = bid << 6;
    const int batch = phys & 7;
    const floatx4 zero = {0.f, 0.f, 0.f, 0.f};

    // ---- LOADX: x_in -> xf32 + xt ----
    {
        const int r = tid >> 3, seg = tid & 7;
        const float4* src = (const float4*)(P.x_in + (size_t)(p0 + r) * 128 + seg * 16);
        float4* dstf = (float4*)&xf32[r * 128 + seg * 16];
#pragma unroll
        for (int i = 0; i < 2; ++i) {
            float4 a = src[2 * i];
            float4 b = src[2 * i + 1];
            dstf[2 * i]     = a;
            dstf[2 * i + 1] = b;
            int kq = seg * 2 + i;
            uint4 pk;
            pk.x = (unsigned int)f2bf(a.x) | ((unsigned int)f2bf(a.y) << 16);
            pk.y = (unsigned int)f2bf(a.z) | ((unsigned int)f2bf(a.w) << 16);
            pk.z = (unsigned int)f2bf(b.x) | ((unsigned int)f2bf(b.y) << 16);
            pk.w = (unsigned int)f2bf(b.z) | ((unsigned int)f2bf(b.w) << 16);
            *(uint4*)&xt[(r * 16 + (kq ^ (r & 7))) * 8] = pk;
        }
    }
    __syncthreads();

    // ---- FFN (2 slices of 256 hid); epilogue: residual into xf32 (+xt) ----
    auto ffn_body = [&](int tf, bool final_out) {
        floatx4 acc2[4];
#pragma unroll
        for (int i = 0; i < 4; ++i) acc2[i] = zero;
        const unsigned short* W1 = P.W1P[tf];
        const unsigned short* W2 = P.W2P[tf];
        const float* b1 = P.b1s[tf];
#pragma unroll
        for (int hf2 = 0; hf2 < 2; ++hf2) {
#pragma unroll
            for (int hh = 0; hh < 2; ++hh) {
                const int hf = 2 * hf2 + hh;
                floatx4 acc1[4];
#pragma unroll
                for (int i = 0; i < 4; ++i) acc1[i] = zero;
                const unsigned short* a1 = W1 + hf * 16384 + w * 2048 + q * 128 + ln * 8;
                __builtin_amdgcn_s_setprio(1);
#pragma unroll
                for (int ks = 0; ks < 4; ++ks) {
                    bf16x8 af = *(const bf16x8*)(a1 + ks * 512);
#pragma unroll
                    for (int nt = 0; nt < 4; ++nt) {
                        bf16x8 bfr = *(const bf16x8*)&xt[((16 * nt + ln) * 16 + ((4 * ks + q) ^ sw)) * 8];
                        acc1[nt] = __builtin_amdgcn_mfma_f32_16x16x32_bf16(af, bfr, acc1[nt], 0, 0, 0);
                    }
                }
                __builtin_amdgcn_s_setprio(0);
                {   // epilogue1: +b1, relu, pack -> ht bank hh
                    const int hid0 = 16 * w + 4 * q;
                    const int ghid = 128 * hf + hid0;
                    const float bv0 = b1[ghid + 0], bv1 = b1[ghid + 1];
                    const float bv2 = b1[ghid + 2], bv3 = b1[ghid + 3];
                    const int c16  = hid0 >> 3;
                    const int half = q & 1;
#pragma unroll
                    for (int nt = 0; nt < 4; ++nt) {
                        const int pt = 16 * nt + ln;
                        float v0 = acc1[nt][0] + bv0; v0 = v0 > 0.f ? v0 : 0.f;
                        float v1 = acc1[nt][1] + bv1; v1 = v1 > 0.f ? v1 : 0.f;
                        float v2 = acc1[nt][2] + bv2; v2 = v2 > 0.f ? v2 : 0.f;
                        float v3 = acc1[nt][3] + bv3; v3 = v3 > 0.f ? v3 : 0.f;
                        uint2 pk;
                        pk.x = (unsigned int)f2bf(v0) | ((unsigned int)f2bf(v1) << 16);
                        pk.y = (unsigned int)f2bf(v2) | ((unsigned int)f2bf(v3) << 16);
                        ht2[hh][(pt * 16 + (c16 ^ (pt & 7))) * 2 + half] = pk;
                    }
                }
            }
            __syncthreads();
            __builtin_amdgcn_s_setprio(1);
#pragma unroll
            for (int hh = 0; hh < 2; ++hh) {
                const int hf = 2 * hf2 + hh;
                const unsigned short* b2b = W2 + hf * 16384 + w * 2048 + q * 128 + ln * 8;
#pragma unroll
                for (int ks = 0; ks < 4; ++ks) {
                    bf16x8 bw = *(const bf16x8*)(b2b + ks * 512);
#pragma unroll
                    for (int mt = 0; mt < 4; ++mt) {
                        bf16x8 ah = *(const bf16x8*)&ht2[hh][((16 * mt + ln) * 16 + ((4 * ks + q) ^ sw)) * 2];
                        acc2[mt] = __builtin_amdgcn_mfma_f32_16x16x32_bf16(ah, bw, acc2[mt], 0, 0, 0);
                    }
                }
            }
            __builtin_amdgcn_s_setprio(0);
            if (hf2 == 0) __syncthreads();
        }
        // epilogue2: +b2, BN, residual from xf32
        const float* b2   = P.b2s[tf];
        const float* gam  = P.gs[tf];
        const float* bet  = P.bes[tf];
        const float* mean = P.ms[tf];
        const float* var  = P.vvs[tf];
        const int c = 16 * w + ln;
        const float bia = b2[c];
        const float sc  = gam[c] * rsqrtf(var[c] + EPS);
        const float bb  = bet[c];
        const float mu  = mean[c];
#pragma unroll
        for (int mt = 0; mt < 4; ++mt) {
#pragma unroll
            for (int r = 0; r < 4; ++r) {
                const int rl = 16 * mt + 4 * q + r;
                float vv = acc2[mt][r] + bia;
                float y  = (vv - mu) * sc + bb;
                float xn = xf32[rl * 128 + c] + y;
                if (final_out) {
                    P.xf[(size_t)(p0 + rl) * 128 + c] = xn;
                } else {
                    xf32[rl * 128 + c] = xn;
                    xt[(rl * 16 + ((c >> 3) ^ (rl & 7))) * 8 + (c & 7)] = f2bf(xn);
                }
            }
        }
    };

    // ---- VFR linear: xt @ Wv -> VbOut (bf16 global) ----
    auto vfr_body = [&](int tv, unsigned short* VbOut) {
        __syncthreads();
        const unsigned short* VT = P.VTP[tv];
        const float* vb = P.vbb[tv];
        floatx4 acc[4];
#pragma unroll
        for (int i = 0; i < 4; ++i) acc[i] = zero;
        const unsigned short* bb2 = VT + w * 2048 + q * 128 + ln * 8;
        __builtin_amdgcn_s_setprio(1);
#pragma unroll
        for (int ks = 0; ks < 4; ++ks) {
            bf16x8 bw = *(const bf16x8*)(bb2 + ks * 512);
#pragma unroll
            for (int mt = 0; mt < 4; ++mt) {
                bf16x8 ax = *(const bf16x8*)&xt[((16 * mt + ln) * 16 + ((4 * ks + q) ^ sw)) * 8];
                acc[mt] = __builtin_amdgcn_mfma_f32_16x16x32_bf16(ax, bw, acc[mt], 0, 0, 0);
            }
        }
        __builtin_amdgcn_s_setprio(0);
        const int c = 16 * w + ln;
        const float bia = vb[c];
#pragma unroll
        for (int mt = 0; mt < 4; ++mt)
#pragma unroll
            for (int r = 0; r < 4; ++r)
                VbOut[(size_t)(p0 + 16 * mt + 4 * q + r) * 128 + c] = f2bf(acc[mt][r] + bia);
    };

    // ---- edge phase: gather-max over Vb, BN, residual into xf32/xt ----
    auto te_body = [&](int te, const unsigned short* VbIn) {
        const int c0 = lane << 1;
        float2 gv = *(const float2*)(P.vgg[te] + c0);
        float2 bv = *(const float2*)(P.vbt[te] + c0);
        float2 mv = *(const float2*)(P.vmm[te] + c0);
        float2 vvv = *(const float2*)(P.vva[te] + c0);
        const float sc0 = gv.x * rsqrtf(vvv.x + EPS);
        const float sc1 = gv.y * rsqrtf(vvv.y + EPS);
#pragma unroll
        for (int it = 0; it < 8; ++it) {
            const int pl = it * 8 + w;
            const int p  = p0 + pl;
            const int b  = p >> 12;
            const size_t rowoff = (size_t)p * 128 + c0;
            unsigned int su = *(const unsigned int*)(VbIn + rowoff);
            const int4* kp4 = (const int4*)(P.knn + (size_t)p * 16);
            int4 ka = kp4[0], kb = kp4[1], kc = kp4[2], kd = kp4[3];
            const unsigned short* vbase = VbIn + (((size_t)b << 12) << 7) + c0;
            float m0 = -3.4e38f, m1 = -3.4e38f;
            unsigned int u;
#define GATH(IDX) u = *(const unsigned int*)(vbase + ((size_t)(IDX) << 7)); \
            m0 = fmaxf(m0, bf2f(u & 0xffffu)); m1 = fmaxf(m1, bf2f(u >> 16));
            GATH(ka.x) GATH(ka.y) GATH(ka.z) GATH(ka.w)
            GATH(kb.x) GATH(kb.y) GATH(kb.z) GATH(kb.w)
            GATH(kc.x) GATH(kc.y) GATH(kc.z) GATH(kc.w)
            GATH(kd.x) GATH(kd.y) GATH(kd.z) GATH(kd.w)
#undef GATH
            float s0 = bf2f(su & 0xffffu), s1 = bf2f(su >> 16);
            float y0 = (m0 - s0 - mv.x) * sc0 + bv.x;
            float y1 = (m1 - s1 - mv.y) * sc1 + bv.y;
            float2 xv = *(const float2*)&xf32[pl * 128 + c0];    // residual from LDS
            float xn0 = xv.x + y0, xn1 = xv.y + y1;
            *(float2*)&xf32[pl * 128 + c0] = make_float2(xn0, xn1);
            unsigned int pk = (unsigned int)f2bf(xn0) | ((unsigned int)f2bf(xn1) << 16);
            ((unsigned int*)xt)[(pl * 16 + ((lane >> 2) ^ (pl & 7))) * 4 + (lane & 3)] = pk;
        }
    };

    // ---- per-batch 64-block barrier (monotonic counter, bounded spin) ----
    auto bbar = [&](unsigned int target) {
        __syncthreads();                      // drains vmcnt: Vb stores complete
        if (tid == 0) {
            __hip_atomic_fetch_add(&P.ctr[batch], 1u, __ATOMIC_RELEASE,
                                   __HIP_MEMORY_SCOPE_AGENT);
            unsigned int spins = 0;
            while (__hip_atomic_load(&P.ctr[batch], __ATOMIC_ACQUIRE,
                                     __HIP_MEMORY_SCOPE_AGENT) < target
                   && spins < 2000000u) {
                ++spins;
                __builtin_amdgcn_s_sleep(8);
            }
        }
        __syncthreads();
    };

    // ---- the network ----
    ffn_body(0, false);
    vfr_body(0, P.Vb0);
    bbar(64);
    te_body(0, P.Vb0);
    __syncthreads();
    ffn_body(1, false);
    vfr_body(1, P.Vb1);
    bbar(128);
    te_body(1, P.Vb1);
    __syncthreads();
    ffn_body(2, true);
}

// ---------------- launch ----------------
extern "C" void kernel_launch(void* const* d_in, const int* in_sizes, int n_in,
                              void* d_out, int out_size, void* d_ws, size_t ws_size,
                              hipStream_t stream)
{
    Params2 p;
    p.x_in = (const float*)d_in[0];
    p.knn  = (const int*)d_in[1];
    const float* w1  = (const float*)d_in[2];
    const float* b1  = (const float*)d_in[3];
    const float* w2  = (const float*)d_in[4];
    const float* b2  = (const float*)d_in[5];
    const float* g0  = (const float*)d_in[6];
    const float* be0 = (const float*)d_in[7];
    const float* m0p = (const float*)d_in[8];
    const float* v0p = (const float*)d_in[9];
    const float* vw  = (const float*)d_in[10];
    const float* vbp = (const float*)d_in[11];
    const float* vgp = (const float*)d_in[12];
    const float* vbe = (const float*)d_in[13];
    const float* vmp = (const float*)d_in[14];
    const float* vvp = (const float*)d_in[15];
    const float* fw1 = (const float*)d_in[16];
    const float* fb1 = (const float*)d_in[17];
    const float* fw2 = (const float*)d_in[18];
    const float* fb2 = (const float*)d_in[19];
    const float* fg  = (const float*)d_in[20];
    const float* fbe = (const float*)d_in[21];
    const float* fm  = (const float*)d_in[22];
    const float* fv  = (const float*)d_in[23];

    p.w1s[0] = w1;  p.w1s[1] = fw1; p.w1s[2] = fw1 + 65536;
    p.w2s[0] = w2;  p.w2s[1] = fw2; p.w2s[2] = fw2 + 65536;
    p.vws[0] = vw;  p.vws[1] = vw + 16384;
    p.b1s[0] = b1;  p.b1s[1] = fb1; p.b1s[2] = fb1 + 512;
    p.b2s[0] = b2;  p.b2s[1] = fb2; p.b2s[2] = fb2 + 128;
    p.gs[0]  = g0;  p.gs[1]  = fg;  p.gs[2]  = fg + 128;
    p.bes[0] = be0; p.bes[1] = fbe; p.bes[2] = fbe + 128;
    p.ms[0]  = m0p; p.ms[1]  = fm;  p.ms[2]  = fm + 128;
    p.vvs[0] = v0p; p.vvs[1] = fv;  p.vvs[2] = fv + 128;
    p.vbb[0] = vbp; p.vbb[1] = vbp + 128;
    p.vgg[0] = vgp; p.vgg[1] = vgp + 128;
    p.vbt[0] = vbe; p.vbt[1] = vbe + 128;
    p.vmm[0] = vmp; p.vmm[1] = vmp + 128;
    p.vva[0] = vvp; p.vva[1] = vvp + 128;

    char* ws = (char*)d_ws;
    p.Vb0 = (unsigned short*)ws;                           // 8 MiB
    p.Vb1 = (unsigned short*)(ws + (size_t)(8 << 20));     // 8 MiB
    unsigned short* u = (unsigned short*)(ws + (size_t)(16 << 20));
    for (int i = 0; i < 3; ++i) p.W1P[i] = u + i * 65536;
    for (int i = 0; i < 3; ++i) p.W2P[i] = u + 196608 + i * 65536;
    for (int i = 0; i < 2; ++i) p.VTP[i] = u + 393216 + i * 16384;
    p.ctr = (unsigned int*)(ws + (size_t)(17 << 20));      // 16 uints
    p.xf  = (float*)d_out;

    pack2<<<dim3(209), 256, 0, stream>>>(p);
    fused<<<dim3(512), dim3(512), 0, stream>>>(p);
}

// Round 4
// 318.468 us; speedup vs baseline: 1.3434x; 1.3434x over previous
//
#include <hip/hip_runtime.h>
#include <hip/hip_bf16.h>
#include <stdint.h>

typedef __attribute__((ext_vector_type(8))) __bf16 bf16x8;
typedef __attribute__((ext_vector_type(4))) float floatx4;

#define EPS 1e-5f

__device__ __forceinline__ unsigned short f2bf(float f) {
    union { float f; unsigned int u; } x; x.f = f;
    unsigned int r = x.u + 0x7fffu + ((x.u >> 16) & 1u);
    return (unsigned short)(r >> 16);
}

__device__ __forceinline__ float bf2f(unsigned int u) {
    union { unsigned int u; float f; } x; x.u = u << 16; return x.f;
}

struct Params2 {
    const float* x_in;
    const int*   knn;
    const float* w1s[3];   // [128][512]
    const float* w2s[3];   // [512][128]
    const float* vws[2];   // [128][128]
    unsigned short* W1P[3];
    unsigned short* W2P[3];
    unsigned short* VTP[2];
    const float* b1s[3];
    const float* b2s[3];
    const float* gs[3];
    const float* bes[3];
    const float* ms[3];
    const float* vvs[3];
    const float* vbb[2];
    const float* vgg[2];
    const float* vbt[2];
    const float* vmm[2];
    const float* vva[2];
    unsigned short* Vb0;
    unsigned short* Vb1;
    unsigned int*   ctr;    // 16 counters, padded: ctr[batch*32]
    float* xf;
};

// ---------------- pack weights, DEST-major (coalesced uint4 stores) --------
// Fragment layout (consumer side, unchanged):
// W1P short-addr d = hf*16384 + w*2048 + ks*512 + q*128 + ln*8 + j
//   holds W1[k=32ks+8q+j][h=128hf+16w+ln]   (src [128][512], idx=k*512+h)
// W2P same d-layout, holds W2[h=128hf+32ks+8q+j][c=16w+ln]  (src idx=h*128+c)
// VTP d = w*2048+ks*512+q*128+ln*8+j, holds Wv[k=32ks+8q+j][c=16w+ln]
// One thread per 8-short fragment -> 16B uint4 store, coalesced.
// Also zeroes the (padded) barrier counters each run.
__global__ __launch_bounds__(256) void pack2(Params2 P) {
    const int gtid = blockIdx.x * 256 + threadIdx.x;
    unsigned short v[8];
    if (gtid < 24576) {                       // W1 x3: 3*8192 fragments
        const int t = gtid >> 13;
        const int d = (gtid & 8191) << 3;
        const int hf = d >> 14, w = (d >> 11) & 7, ks = (d >> 9) & 3,
                  q = (d >> 7) & 3, ln = (d >> 3) & 15;
        const float* s1 = P.w1s[t];
        const int hcol = 128 * hf + 16 * w + ln;
        const int kb   = 32 * ks + 8 * q;
#pragma unroll
        for (int j = 0; j < 8; ++j) v[j] = f2bf(s1[(kb + j) * 512 + hcol]);
        uint4 pk;
        pk.x = v[0] | ((unsigned)v[1] << 16); pk.y = v[2] | ((unsigned)v[3] << 16);
        pk.z = v[4] | ((unsigned)v[5] << 16); pk.w = v[6] | ((unsigned)v[7] << 16);
        *(uint4*)&P.W1P[t][d] = pk;
    } else if (gtid < 49152) {                // W2 x3: 3*8192 fragments
        const int g = gtid - 24576;
        const int t = g >> 13;
        const int d = (g & 8191) << 3;
        const int hf = d >> 14, w = (d >> 11) & 7, ks = (d >> 9) & 3,
                  q = (d >> 7) & 3, ln = (d >> 3) & 15;
        const float* s2 = P.w2s[t];
        const int col = 16 * w + ln;
        const int hb  = 128 * hf + 32 * ks + 8 * q;
#pragma unroll
        for (int j = 0; j < 8; ++j) v[j] = f2bf(s2[(hb + j) * 128 + col]);
        uint4 pk;
        pk.x = v[0] | ((unsigned)v[1] << 16); pk.y = v[2] | ((unsigned)v[3] << 16);
        pk.z = v[4] | ((unsigned)v[5] << 16); pk.w = v[6] | ((unsigned)v[7] << 16);
        *(uint4*)&P.W2P[t][d] = pk;
    } else if (gtid < 53248) {                // VT x2: 2*2048 fragments
        const int g = gtid - 49152;
        const int t = g >> 11;
        const int d = (g & 2047) << 3;
        const int w = (d >> 11) & 7, ks = (d >> 9) & 3,
                  q = (d >> 7) & 3, ln = (d >> 3) & 15;
        const float* sv = P.vws[t];
        const int col = 16 * w + ln;
        const int kb  = 32 * ks + 8 * q;
#pragma unroll
        for (int j = 0; j < 8; ++j) v[j] = f2bf(sv[(kb + j) * 128 + col]);
        uint4 pk;
        pk.x = v[0] | ((unsigned)v[1] << 16); pk.y = v[2] | ((unsigned)v[3] << 16);
        pk.z = v[4] | ((unsigned)v[5] << 16); pk.w = v[6] | ((unsigned)v[7] << 16);
        *(uint4*)&P.VTP[t][d] = pk;
    } else if (gtid < 53760) {
        P.ctr[gtid - 53248] = 0;              // padded counters (512 words)
    }
}

// ---------------- fully fused kernel (plain launch, capacity-resident) -----
// 512 blocks x 512 thr (8 waves), 80 KB LDS, __launch_bounds__(512,4)
// => <=128 VGPR, exactly 2 blocks/CU, grid == 2 x 256 CU: ALL blocks
// resident at dispatch. x stays in LDS across all 3 logical stages.
// Cross-block dep (batch-local KNN gather) handled by per-batch 64-block
// spin barriers. R3 LESSON: acquire-per-spin-iteration emits an L2
// invalidate each poll -> invalidate storm nuked the whole chip's L2
// (FETCH 103MB/WRITE 180MB, MfmaUtil 3.9%). Fix: RELAXED spin loads
// (per-load coherent read, no cache maintenance) + ONE release fence
// before the add + ONE acquire fence after spin exit; counters padded
// to one per 128B line. Spin is bounded so a violated residency
// assumption fails cleanly instead of hanging.
__global__ __launch_bounds__(512, 4)
void fused(Params2 P)
{
    __shared__ __align__(16) unsigned short xt[8192];   // 16 KB bf16 x tile
    __shared__ __align__(16) float xf32[8192];          // 32 KB fp32 x tile
    __shared__ __align__(16) uint2 ht2[2][2048];        // 32 KB h banks
    const int tid  = threadIdx.x;
    const int lane = tid & 63;
    const int w    = tid >> 6;       // wave 0..7
    const int q    = lane >> 4;
    const int ln   = lane & 15;
    const int sw   = ln & 7;
    const int phys = blockIdx.x;
    const int bid  = (phys & 7) * 64 + (phys >> 3);   // XCD-local batches
    const int p0   = bid << 6;
    const int batch = phys & 7;
    const floatx4 zero = {0.f, 0.f, 0.f, 0.f};

    // ---- LOADX: x_in -> xf32 + xt ----
    {
        const int r = tid >> 3, seg = tid & 7;
        const float4* src = (const float4*)(P.x_in + (size_t)(p0 + r) * 128 + seg * 16);
        float4* dstf = (float4*)&xf32[r * 128 + seg * 16];
#pragma unroll
        for (int i = 0; i < 2; ++i) {
            float4 a = src[2 * i];
            float4 b = src[2 * i + 1];
            dstf[2 * i]     = a;
            dstf[2 * i + 1] = b;
            int kq = seg * 2 + i;
            uint4 pk;
            pk.x = (unsigned int)f2bf(a.x) | ((unsigned int)f2bf(a.y) << 16);
            pk.y = (unsigned int)f2bf(a.z) | ((unsigned int)f2bf(a.w) << 16);
            pk.z = (unsigned int)f2bf(b.x) | ((unsigned int)f2bf(b.y) << 16);
            pk.w = (unsigned int)f2bf(b.z) | ((unsigned int)f2bf(b.w) << 16);
            *(uint4*)&xt[(r * 16 + (kq ^ (r & 7))) * 8] = pk;
        }
    }
    __syncthreads();

    // ---- FFN (2 slices of 256 hid); epilogue: residual into xf32 (+xt) ----
    auto ffn_body = [&](int tf, bool final_out) {
        floatx4 acc2[4];
#pragma unroll
        for (int i = 0; i < 4; ++i) acc2[i] = zero;
        const unsigned short* W1 = P.W1P[tf];
        const unsigned short* W2 = P.W2P[tf];
        const float* b1 = P.b1s[tf];
#pragma unroll
        for (int hf2 = 0; hf2 < 2; ++hf2) {
#pragma unroll
            for (int hh = 0; hh < 2; ++hh) {
                const int hf = 2 * hf2 + hh;
                floatx4 acc1[4];
#pragma unroll
                for (int i = 0; i < 4; ++i) acc1[i] = zero;
                const unsigned short* a1 = W1 + hf * 16384 + w * 2048 + q * 128 + ln * 8;
                __builtin_amdgcn_s_setprio(1);
#pragma unroll
                for (int ks = 0; ks < 4; ++ks) {
                    bf16x8 af = *(const bf16x8*)(a1 + ks * 512);
#pragma unroll
                    for (int nt = 0; nt < 4; ++nt) {
                        bf16x8 bfr = *(const bf16x8*)&xt[((16 * nt + ln) * 16 + ((4 * ks + q) ^ sw)) * 8];
                        acc1[nt] = __builtin_amdgcn_mfma_f32_16x16x32_bf16(af, bfr, acc1[nt], 0, 0, 0);
                    }
                }
                __builtin_amdgcn_s_setprio(0);
                {   // epilogue1: +b1, relu, pack -> ht bank hh
                    const int hid0 = 16 * w + 4 * q;
                    const int ghid = 128 * hf + hid0;
                    const float bv0 = b1[ghid + 0], bv1 = b1[ghid + 1];
                    const float bv2 = b1[ghid + 2], bv3 = b1[ghid + 3];
                    const int c16  = hid0 >> 3;
                    const int half = q & 1;
#pragma unroll
                    for (int nt = 0; nt < 4; ++nt) {
                        const int pt = 16 * nt + ln;
                        float v0 = acc1[nt][0] + bv0; v0 = v0 > 0.f ? v0 : 0.f;
                        float v1 = acc1[nt][1] + bv1; v1 = v1 > 0.f ? v1 : 0.f;
                        float v2 = acc1[nt][2] + bv2; v2 = v2 > 0.f ? v2 : 0.f;
                        float v3 = acc1[nt][3] + bv3; v3 = v3 > 0.f ? v3 : 0.f;
                        uint2 pk;
                        pk.x = (unsigned int)f2bf(v0) | ((unsigned int)f2bf(v1) << 16);
                        pk.y = (unsigned int)f2bf(v2) | ((unsigned int)f2bf(v3) << 16);
                        ht2[hh][(pt * 16 + (c16 ^ (pt & 7))) * 2 + half] = pk;
                    }
                }
            }
            __syncthreads();
            __builtin_amdgcn_s_setprio(1);
#pragma unroll
            for (int hh = 0; hh < 2; ++hh) {
                const int hf = 2 * hf2 + hh;
                const unsigned short* b2b = W2 + hf * 16384 + w * 2048 + q * 128 + ln * 8;
#pragma unroll
                for (int ks = 0; ks < 4; ++ks) {
                    bf16x8 bw = *(const bf16x8*)(b2b + ks * 512);
#pragma unroll
                    for (int mt = 0; mt < 4; ++mt) {
                        bf16x8 ah = *(const bf16x8*)&ht2[hh][((16 * mt + ln) * 16 + ((4 * ks + q) ^ sw)) * 2];
                        acc2[mt] = __builtin_amdgcn_mfma_f32_16x16x32_bf16(ah, bw, acc2[mt], 0, 0, 0);
                    }
                }
            }
            __builtin_amdgcn_s_setprio(0);
            if (hf2 == 0) __syncthreads();
        }
        // epilogue2: +b2, BN, residual from xf32
        const float* b2   = P.b2s[tf];
        const float* gam  = P.gs[tf];
        const float* bet  = P.bes[tf];
        const float* mean = P.ms[tf];
        const float* var  = P.vvs[tf];
        const int c = 16 * w + ln;
        const float bia = b2[c];
        const float sc  = gam[c] * rsqrtf(var[c] + EPS);
        const float bb  = bet[c];
        const float mu  = mean[c];
#pragma unroll
        for (int mt = 0; mt < 4; ++mt) {
#pragma unroll
            for (int r = 0; r < 4; ++r) {
                const int rl = 16 * mt + 4 * q + r;
                float vv = acc2[mt][r] + bia;
                float y  = (vv - mu) * sc + bb;
                float xn = xf32[rl * 128 + c] + y;
                if (final_out) {
                    P.xf[(size_t)(p0 + rl) * 128 + c] = xn;
                } else {
                    xf32[rl * 128 + c] = xn;
                    xt[(rl * 16 + ((c >> 3) ^ (rl & 7))) * 8 + (c & 7)] = f2bf(xn);
                }
            }
        }
    };

    // ---- VFR linear: xt @ Wv -> VbOut (bf16 global) ----
    auto vfr_body = [&](int tv, unsigned short* VbOut) {
        __syncthreads();
        const unsigned short* VT = P.VTP[tv];
        const float* vb = P.vbb[tv];
        floatx4 acc[4];
#pragma unroll
        for (int i = 0; i < 4; ++i) acc[i] = zero;
        const unsigned short* bb2 = VT + w * 2048 + q * 128 + ln * 8;
        __builtin_amdgcn_s_setprio(1);
#pragma unroll
        for (int ks = 0; ks < 4; ++ks) {
            bf16x8 bw = *(const bf16x8*)(bb2 + ks * 512);
#pragma unroll
            for (int mt = 0; mt < 4; ++mt) {
                bf16x8 ax = *(const bf16x8*)&xt[((16 * mt + ln) * 16 + ((4 * ks + q) ^ sw)) * 8];
                acc[mt] = __builtin_amdgcn_mfma_f32_16x16x32_bf16(ax, bw, acc[mt], 0, 0, 0);
            }
        }
        __builtin_amdgcn_s_setprio(0);
        const int c = 16 * w + ln;
        const float bia = vb[c];
#pragma unroll
        for (int mt = 0; mt < 4; ++mt)
#pragma unroll
            for (int r = 0; r < 4; ++r)
                VbOut[(size_t)(p0 + 16 * mt + 4 * q + r) * 128 + c] = f2bf(acc[mt][r] + bia);
    };

    // ---- edge phase: gather-max over Vb, BN, residual into xf32/xt ----
    auto te_body = [&](int te, const unsigned short* VbIn) {
        const int c0 = lane << 1;
        float2 gv = *(const float2*)(P.vgg[te] + c0);
        float2 bv = *(const float2*)(P.vbt[te] + c0);
        float2 mv = *(const float2*)(P.vmm[te] + c0);
        float2 vvv = *(const float2*)(P.vva[te] + c0);
        const float sc0 = gv.x * rsqrtf(vvv.x + EPS);
        const float sc1 = gv.y * rsqrtf(vvv.y + EPS);
#pragma unroll
        for (int it = 0; it < 8; ++it) {
            const int pl = it * 8 + w;
            const int p  = p0 + pl;
            const int b  = p >> 12;
            const size_t rowoff = (size_t)p * 128 + c0;
            unsigned int su = *(const unsigned int*)(VbIn + rowoff);
            const int4* kp4 = (const int4*)(P.knn + (size_t)p * 16);
            int4 ka = kp4[0], kb = kp4[1], kc = kp4[2], kd = kp4[3];
            const unsigned short* vbase = VbIn + (((size_t)b << 12) << 7) + c0;
            float m0 = -3.4e38f, m1 = -3.4e38f;
            unsigned int u;
#define GATH(IDX) u = *(const unsigned int*)(vbase + ((size_t)(IDX) << 7)); \
            m0 = fmaxf(m0, bf2f(u & 0xffffu)); m1 = fmaxf(m1, bf2f(u >> 16));
            GATH(ka.x) GATH(ka.y) GATH(ka.z) GATH(ka.w)
            GATH(kb.x) GATH(kb.y) GATH(kb.z) GATH(kb.w)
            GATH(kc.x) GATH(kc.y) GATH(kc.z) GATH(kc.w)
            GATH(kd.x) GATH(kd.y) GATH(kd.z) GATH(kd.w)
#undef GATH
            float s0 = bf2f(su & 0xffffu), s1 = bf2f(su >> 16);
            float y0 = (m0 - s0 - mv.x) * sc0 + bv.x;
            float y1 = (m1 - s1 - mv.y) * sc1 + bv.y;
            float2 xv = *(const float2*)&xf32[pl * 128 + c0];    // residual from LDS
            float xn0 = xv.x + y0, xn1 = xv.y + y1;
            *(float2*)&xf32[pl * 128 + c0] = make_float2(xn0, xn1);
            unsigned int pk = (unsigned int)f2bf(xn0) | ((unsigned int)f2bf(xn1) << 16);
            ((unsigned int*)xt)[(pl * 16 + ((lane >> 2) ^ (pl & 7))) * 4 + (lane & 3)] = pk;
        }
    };

    // ---- per-batch 64-block barrier: relaxed spin, single fences ----
    // release fence (once): wb dirty L2 -> coherence point, then relaxed add.
    // relaxed spin: per-load coherent read, NO cache maintenance per poll.
    // acquire fence (once, after exit): invalidate L1/L2 so subsequent
    // gathers see other blocks' Vb writes. Counters padded 128B apart.
    auto bbar = [&](unsigned int target) {
        __syncthreads();                      // vmcnt(0): Vb stores issued-complete
        if (tid == 0) {
            unsigned int* c = &P.ctr[batch << 5];
            __builtin_amdgcn_fence(__ATOMIC_RELEASE, "agent");
            __hip_atomic_fetch_add(c, 1u, __ATOMIC_RELAXED,
                                   __HIP_MEMORY_SCOPE_AGENT);
            unsigned int spins = 0;
            while (__hip_atomic_load(c, __ATOMIC_RELAXED,
                                     __HIP_MEMORY_SCOPE_AGENT) < target
                   && spins < 4000000u) {
                ++spins;
                __builtin_amdgcn_s_sleep(2);
            }
            __builtin_amdgcn_fence(__ATOMIC_ACQUIRE, "agent");
        }
        __syncthreads();
    };

    // ---- the network ----
    ffn_body(0, false);
    vfr_body(0, P.Vb0);
    bbar(64);
    te_body(0, P.Vb0);
    __syncthreads();
    ffn_body(1, false);
    vfr_body(1, P.Vb1);
    bbar(128);
    te_body(1, P.Vb1);
    __syncthreads();
    ffn_body(2, true);
}

// ---------------- launch ----------------
extern "C" void kernel_launch(void* const* d_in, const int* in_sizes, int n_in,
                              void* d_out, int out_size, void* d_ws, size_t ws_size,
                              hipStream_t stream)
{
    Params2 p;
    p.x_in = (const float*)d_in[0];
    p.knn  = (const int*)d_in[1];
    const float* w1  = (const float*)d_in[2];
    const float* b1  = (const float*)d_in[3];
    const float* w2  = (const float*)d_in[4];
    const float* b2  = (const float*)d_in[5];
    const float* g0  = (const float*)d_in[6];
    const float* be0 = (const float*)d_in[7];
    const float* m0p = (const float*)d_in[8];
    const float* v0p = (const float*)d_in[9];
    const float* vw  = (const float*)d_in[10];
    const float* vbp = (const float*)d_in[11];
    const float* vgp = (const float*)d_in[12];
    const float* vbe = (const float*)d_in[13];
    const float* vmp = (const float*)d_in[14];
    const float* vvp = (const float*)d_in[15];
    const float* fw1 = (const float*)d_in[16];
    const float* fb1 = (const float*)d_in[17];
    const float* fw2 = (const float*)d_in[18];
    const float* fb2 = (const float*)d_in[19];
    const float* fg  = (const float*)d_in[20];
    const float* fbe = (const float*)d_in[21];
    const float* fm  = (const float*)d_in[22];
    const float* fv  = (const float*)d_in[23];

    p.w1s[0] = w1;  p.w1s[1] = fw1; p.w1s[2] = fw1 + 65536;
    p.w2s[0] = w2;  p.w2s[1] = fw2; p.w2s[2] = fw2 + 65536;
    p.vws[0] = vw;  p.vws[1] = vw + 16384;
    p.b1s[0] = b1;  p.b1s[1] = fb1; p.b1s[2] = fb1 + 512;
    p.b2s[0] = b2;  p.b2s[1] = fb2; p.b2s[2] = fb2 + 128;
    p.gs[0]  = g0;  p.gs[1]  = fg;  p.gs[2]  = fg + 128;
    p.bes[0] = be0; p.bes[1] = fbe; p.bes[2] = fbe + 128;
    p.ms[0]  = m0p; p.ms[1]  = fm;  p.ms[2]  = fm + 128;
    p.vvs[0] = v0p; p.vvs[1] = fv;  p.vvs[2] = fv + 128;
    p.vbb[0] = vbp; p.vbb[1] = vbp + 128;
    p.vgg[0] = vgp; p.vgg[1] = vgp + 128;
    p.vbt[0] = vbe; p.vbt[1] = vbe + 128;
    p.vmm[0] = vmp; p.vmm[1] = vmp + 128;
    p.vva[0] = vvp; p.vva[1] = vvp + 128;

    char* ws = (char*)d_ws;
    p.Vb0 = (unsigned short*)ws;                           // 8 MiB
    p.Vb1 = (unsigned short*)(ws + (size_t)(8 << 20));     // 8 MiB
    unsigned short* u = (unsigned short*)(ws + (size_t)(16 << 20));
    for (int i = 0; i < 3; ++i) p.W1P[i] = u + i * 65536;
    for (int i = 0; i < 3; ++i) p.W2P[i] = u + 196608 + i * 65536;
    for (int i = 0; i < 2; ++i) p.VTP[i] = u + 393216 + i * 16384;
    p.ctr = (unsigned int*)(ws + (size_t)(17 << 20));      // 512 padded words
    p.xf  = (float*)d_out;

    pack2<<<dim3(210), 256, 0, stream>>>(p);
    fused<<<dim3(512), dim3(512), 0, stream>>>(p);
}

// Round 5
// 279.326 us; speedup vs baseline: 1.5316x; 1.1401x over previous
//
#include <hip/hip_runtime.h>
#include <hip/hip_bf16.h>
#include <stdint.h>

typedef __attribute__((ext_vector_type(8))) __bf16 bf16x8;
typedef __attribute__((ext_vector_type(4))) float floatx4;

#define EPS 1e-5f

__device__ __forceinline__ unsigned short f2bf(float f) {
    union { float f; unsigned int u; } x; x.f = f;
    unsigned int r = x.u + 0x7fffu + ((x.u >> 16) & 1u);
    return (unsigned short)(r >> 16);
}

__device__ __forceinline__ float bf2f(unsigned int u) {
    union { unsigned int u; float f; } x; x.u = u << 16; return x.f;
}

struct Params2 {
    const float* x_in;
    const int*   knn;
    const float* w1s[3];   // [128][512]
    const float* w2s[3];   // [512][128]
    const float* vws[2];   // [128][128]
    unsigned short* W1P[3];
    unsigned short* W2P[3];
    unsigned short* VTP[2];
    const float* b1s[3];
    const float* b2s[3];
    const float* gs[3];
    const float* bes[3];
    const float* ms[3];
    const float* vvs[3];
    const float* vbb[2];
    const float* vgg[2];
    const float* vbt[2];
    const float* vmm[2];
    const float* vva[2];
    unsigned short* Vb0;
    unsigned short* Vb1;
    unsigned int*   ctr;    // 16 counters, padded: ctr[batch*32]
    float* xf;
};

// ---------------- pack weights, DEST-major (coalesced uint4 stores) --------
// W1P short-addr d = hf*16384 + w*2048 + ks*512 + q*128 + ln*8 + j
//   holds W1[k=32ks+8q+j][h=128hf+16w+ln]   (src [128][512], idx=k*512+h)
// W2P same d-layout, holds W2[h=128hf+32ks+8q+j][c=16w+ln]  (src idx=h*128+c)
// VTP d = w*2048+ks*512+q*128+ln*8+j, holds Wv[k=32ks+8q+j][c=16w+ln]
// One thread per 8-short fragment -> 16B uint4 store, coalesced.
// Also zeroes the (padded) barrier counters each run.
__global__ __launch_bounds__(256) void pack2(Params2 P) {
    const int gtid = blockIdx.x * 256 + threadIdx.x;
    unsigned short v[8];
    if (gtid < 24576) {                       // W1 x3: 3*8192 fragments
        const int t = gtid >> 13;
        const int d = (gtid & 8191) << 3;
        const int hf = d >> 14, w = (d >> 11) & 7, ks = (d >> 9) & 3,
                  q = (d >> 7) & 3, ln = (d >> 3) & 15;
        const float* s1 = P.w1s[t];
        const int hcol = 128 * hf + 16 * w + ln;
        const int kb   = 32 * ks + 8 * q;
#pragma unroll
        for (int j = 0; j < 8; ++j) v[j] = f2bf(s1[(kb + j) * 512 + hcol]);
        uint4 pk;
        pk.x = v[0] | ((unsigned)v[1] << 16); pk.y = v[2] | ((unsigned)v[3] << 16);
        pk.z = v[4] | ((unsigned)v[5] << 16); pk.w = v[6] | ((unsigned)v[7] << 16);
        *(uint4*)&P.W1P[t][d] = pk;
    } else if (gtid < 49152) {                // W2 x3: 3*8192 fragments
        const int g = gtid - 24576;
        const int t = g >> 13;
        const int d = (g & 8191) << 3;
        const int hf = d >> 14, w = (d >> 11) & 7, ks = (d >> 9) & 3,
                  q = (d >> 7) & 3, ln = (d >> 3) & 15;
        const float* s2 = P.w2s[t];
        const int col = 16 * w + ln;
        const int hb  = 128 * hf + 32 * ks + 8 * q;
#pragma unroll
        for (int j = 0; j < 8; ++j) v[j] = f2bf(s2[(hb + j) * 128 + col]);
        uint4 pk;
        pk.x = v[0] | ((unsigned)v[1] << 16); pk.y = v[2] | ((unsigned)v[3] << 16);
        pk.z = v[4] | ((unsigned)v[5] << 16); pk.w = v[6] | ((unsigned)v[7] << 16);
        *(uint4*)&P.W2P[t][d] = pk;
    } else if (gtid < 53248) {                // VT x2: 2*2048 fragments
        const int g = gtid - 49152;
        const int t = g >> 11;
        const int d = (g & 2047) << 3;
        const int w = (d >> 11) & 7, ks = (d >> 9) & 3,
                  q = (d >> 7) & 3, ln = (d >> 3) & 15;
        const float* sv = P.vws[t];
        const int col = 16 * w + ln;
        const int kb  = 32 * ks + 8 * q;
#pragma unroll
        for (int j = 0; j < 8; ++j) v[j] = f2bf(sv[(kb + j) * 128 + col]);
        uint4 pk;
        pk.x = v[0] | ((unsigned)v[1] << 16); pk.y = v[2] | ((unsigned)v[3] << 16);
        pk.z = v[4] | ((unsigned)v[5] << 16); pk.w = v[6] | ((unsigned)v[7] << 16);
        *(uint4*)&P.VTP[t][d] = pk;
    } else if (gtid < 53760) {
        P.ctr[gtid - 53248] = 0;              // padded counters (512 words)
    }
}

// ---------------- fully fused kernel (plain launch, capacity-resident) -----
// 512 blocks x 512 thr (8 waves), 64 KB LDS, __launch_bounds__(512,4)
// => 2 blocks/CU, grid == 2 x 256 CU: all blocks resident at dispatch.
// x stays in LDS across all 3 logical stages. Cross-block dep (batch-local
// KNN gather) via per-batch 64-block spin barriers (relaxed spin, single
// release/acquire fences, padded counters — R4 form).
// R4 LESSON: FETCH/WRITE (103/180 MB) were identical across two different
// barrier implementations -> the ~150 MB excess writes are BODY-structural,
// hypothesis: scratch spills from the 2x256-hid FFN body (3 live floatx4[4]
// accumulator sets) at the 128-reg/lane unified-file cap. THIS ROUND:
// revert to the 4x128-hid slice body (one acc1 live, 16 KB ht bank) to
// drop below the cap. Everything else unchanged from R4.
__global__ __launch_bounds__(512, 4)
void fused(Params2 P)
{
    __shared__ __align__(16) unsigned short xt[8192];   // 16 KB bf16 x tile
    __shared__ __align__(16) float xf32[8192];          // 32 KB fp32 x tile
    __shared__ __align__(16) uint2 ht2[2048];           // 16 KB h bank
    const int tid  = threadIdx.x;
    const int lane = tid & 63;
    const int w    = tid >> 6;       // wave 0..7
    const int q    = lane >> 4;
    const int ln   = lane & 15;
    const int sw   = ln & 7;
    const int phys = blockIdx.x;
    const int bid  = (phys & 7) * 64 + (phys >> 3);   // XCD-local batches
    const int p0   = bid << 6;
    const int batch = phys & 7;
    const floatx4 zero = {0.f, 0.f, 0.f, 0.f};

    // ---- LOADX: x_in -> xf32 + xt ----
    {
        const int r = tid >> 3, seg = tid & 7;
        const float4* src = (const float4*)(P.x_in + (size_t)(p0 + r) * 128 + seg * 16);
        float4* dstf = (float4*)&xf32[r * 128 + seg * 16];
#pragma unroll
        for (int i = 0; i < 2; ++i) {
            float4 a = src[2 * i];
            float4 b = src[2 * i + 1];
            dstf[2 * i]     = a;
            dstf[2 * i + 1] = b;
            int kq = seg * 2 + i;
            uint4 pk;
            pk.x = (unsigned int)f2bf(a.x) | ((unsigned int)f2bf(a.y) << 16);
            pk.y = (unsigned int)f2bf(a.z) | ((unsigned int)f2bf(a.w) << 16);
            pk.z = (unsigned int)f2bf(b.x) | ((unsigned int)f2bf(b.y) << 16);
            pk.w = (unsigned int)f2bf(b.z) | ((unsigned int)f2bf(b.w) << 16);
            *(uint4*)&xt[(r * 16 + (kq ^ (r & 7))) * 8] = pk;
        }
    }
    __syncthreads();

    // ---- FFN, hidden-split x4 (R0 body: one acc1 live, low pressure) ----
    auto ffn_body = [&](int tf, bool final_out) {
        floatx4 acc2[4];
#pragma unroll
        for (int i = 0; i < 4; ++i) acc2[i] = zero;
        const unsigned short* W1 = P.W1P[tf];
        const unsigned short* W2 = P.W2P[tf];
        const float* b1 = P.b1s[tf];
#pragma unroll
        for (int hf = 0; hf < 4; ++hf) {
            // GEMM1: h^T slice (M=128 hid, N=64 pts, K=128)
            floatx4 acc1[4];
#pragma unroll
            for (int i = 0; i < 4; ++i) acc1[i] = zero;
            const unsigned short* a1 = W1 + hf * 16384 + w * 2048 + q * 128 + ln * 8;
            __builtin_amdgcn_s_setprio(1);
#pragma unroll
            for (int ks = 0; ks < 4; ++ks) {
                bf16x8 af = *(const bf16x8*)(a1 + ks * 512);
#pragma unroll
                for (int nt = 0; nt < 4; ++nt) {
                    bf16x8 bfr = *(const bf16x8*)&xt[((16 * nt + ln) * 16 + ((4 * ks + q) ^ sw)) * 8];
                    acc1[nt] = __builtin_amdgcn_mfma_f32_16x16x32_bf16(af, bfr, acc1[nt], 0, 0, 0);
                }
            }
            __builtin_amdgcn_s_setprio(0);
            {   // epilogue1: +b1, relu, pack 4 consecutive hid -> ht
                const int hid0 = 16 * w + 4 * q;          // within this 128-slice
                const int ghid = 128 * hf + hid0;
                const float bv0 = b1[ghid + 0], bv1 = b1[ghid + 1];
                const float bv2 = b1[ghid + 2], bv3 = b1[ghid + 3];
                const int c16  = hid0 >> 3;
                const int half = q & 1;
#pragma unroll
                for (int nt = 0; nt < 4; ++nt) {
                    const int pt = 16 * nt + ln;
                    float v0 = acc1[nt][0] + bv0; v0 = v0 > 0.f ? v0 : 0.f;
                    float v1 = acc1[nt][1] + bv1; v1 = v1 > 0.f ? v1 : 0.f;
                    float v2 = acc1[nt][2] + bv2; v2 = v2 > 0.f ? v2 : 0.f;
                    float v3 = acc1[nt][3] + bv3; v3 = v3 > 0.f ? v3 : 0.f;
                    uint2 pk;
                    pk.x = (unsigned int)f2bf(v0) | ((unsigned int)f2bf(v1) << 16);
                    pk.y = (unsigned int)f2bf(v2) | ((unsigned int)f2bf(v3) << 16);
                    ht2[(pt * 16 + (c16 ^ (pt & 7))) * 2 + half] = pk;
                }
            }
            __syncthreads();
            // GEMM2: y += h_slice @ W2_slice (M=64 pts, N=128 ch, K=128)
            const unsigned short* b2b = W2 + hf * 16384 + w * 2048 + q * 128 + ln * 8;
            __builtin_amdgcn_s_setprio(1);
#pragma unroll
            for (int ks = 0; ks < 4; ++ks) {
                bf16x8 bw = *(const bf16x8*)(b2b + ks * 512);
#pragma unroll
                for (int mt = 0; mt < 4; ++mt) {
                    bf16x8 ah = *(const bf16x8*)&ht2[((16 * mt + ln) * 16 + ((4 * ks + q) ^ sw)) * 2];
                    acc2[mt] = __builtin_amdgcn_mfma_f32_16x16x32_bf16(ah, bw, acc2[mt], 0, 0, 0);
                }
            }
            __builtin_amdgcn_s_setprio(0);
            __syncthreads();
        }
        // epilogue2: +b2, BN, residual from xf32
        const float* b2   = P.b2s[tf];
        const float* gam  = P.gs[tf];
        const float* bet  = P.bes[tf];
        const float* mean = P.ms[tf];
        const float* var  = P.vvs[tf];
        const int c = 16 * w + ln;
        const float bia = b2[c];
        const float sc  = gam[c] * rsqrtf(var[c] + EPS);
        const float bb  = bet[c];
        const float mu  = mean[c];
#pragma unroll
        for (int mt = 0; mt < 4; ++mt) {
#pragma unroll
            for (int r = 0; r < 4; ++r) {
                const int rl = 16 * mt + 4 * q + r;
                float vv = acc2[mt][r] + bia;
                float y  = (vv - mu) * sc + bb;
                float xn = xf32[rl * 128 + c] + y;
                if (final_out) {
                    P.xf[(size_t)(p0 + rl) * 128 + c] = xn;
                } else {
                    xf32[rl * 128 + c] = xn;
                    xt[(rl * 16 + ((c >> 3) ^ (rl & 7))) * 8 + (c & 7)] = f2bf(xn);
                }
            }
        }
    };

    // ---- VFR linear: xt @ Wv -> VbOut (bf16 global) ----
    auto vfr_body = [&](int tv, unsigned short* VbOut) {
        __syncthreads();
        const unsigned short* VT = P.VTP[tv];
        const float* vb = P.vbb[tv];
        floatx4 acc[4];
#pragma unroll
        for (int i = 0; i < 4; ++i) acc[i] = zero;
        const unsigned short* bb2 = VT + w * 2048 + q * 128 + ln * 8;
        __builtin_amdgcn_s_setprio(1);
#pragma unroll
        for (int ks = 0; ks < 4; ++ks) {
            bf16x8 bw = *(const bf16x8*)(bb2 + ks * 512);
#pragma unroll
            for (int mt = 0; mt < 4; ++mt) {
                bf16x8 ax = *(const bf16x8*)&xt[((16 * mt + ln) * 16 + ((4 * ks + q) ^ sw)) * 8];
                acc[mt] = __builtin_amdgcn_mfma_f32_16x16x32_bf16(ax, bw, acc[mt], 0, 0, 0);
            }
        }
        __builtin_amdgcn_s_setprio(0);
        const int c = 16 * w + ln;
        const float bia = vb[c];
#pragma unroll
        for (int mt = 0; mt < 4; ++mt)
#pragma unroll
            for (int r = 0; r < 4; ++r)
                VbOut[(size_t)(p0 + 16 * mt + 4 * q + r) * 128 + c] = f2bf(acc[mt][r] + bia);
    };

    // ---- edge phase: gather-max over Vb, BN, residual into xf32/xt ----
    auto te_body = [&](int te, const unsigned short* VbIn) {
        const int c0 = lane << 1;
        float2 gv = *(const float2*)(P.vgg[te] + c0);
        float2 bv = *(const float2*)(P.vbt[te] + c0);
        float2 mv = *(const float2*)(P.vmm[te] + c0);
        float2 vvv = *(const float2*)(P.vva[te] + c0);
        const float sc0 = gv.x * rsqrtf(vvv.x + EPS);
        const float sc1 = gv.y * rsqrtf(vvv.y + EPS);
#pragma unroll
        for (int it = 0; it < 8; ++it) {
            const int pl = it * 8 + w;
            const int p  = p0 + pl;
            const int b  = p >> 12;
            const size_t rowoff = (size_t)p * 128 + c0;
            unsigned int su = *(const unsigned int*)(VbIn + rowoff);
            const int4* kp4 = (const int4*)(P.knn + (size_t)p * 16);
            int4 ka = kp4[0], kb = kp4[1], kc = kp4[2], kd = kp4[3];
            const unsigned short* vbase = VbIn + (((size_t)b << 12) << 7) + c0;
            float m0 = -3.4e38f, m1 = -3.4e38f;
            unsigned int u;
#define GATH(IDX) u = *(const unsigned int*)(vbase + ((size_t)(IDX) << 7)); \
            m0 = fmaxf(m0, bf2f(u & 0xffffu)); m1 = fmaxf(m1, bf2f(u >> 16));
            GATH(ka.x) GATH(ka.y) GATH(ka.z) GATH(ka.w)
            GATH(kb.x) GATH(kb.y) GATH(kb.z) GATH(kb.w)
            GATH(kc.x) GATH(kc.y) GATH(kc.z) GATH(kc.w)
            GATH(kd.x) GATH(kd.y) GATH(kd.z) GATH(kd.w)
#undef GATH
            float s0 = bf2f(su & 0xffffu), s1 = bf2f(su >> 16);
            float y0 = (m0 - s0 - mv.x) * sc0 + bv.x;
            float y1 = (m1 - s1 - mv.y) * sc1 + bv.y;
            float2 xv = *(const float2*)&xf32[pl * 128 + c0];    // residual from LDS
            float xn0 = xv.x + y0, xn1 = xv.y + y1;
            *(float2*)&xf32[pl * 128 + c0] = make_float2(xn0, xn1);
            unsigned int pk = (unsigned int)f2bf(xn0) | ((unsigned int)f2bf(xn1) << 16);
            ((unsigned int*)xt)[(pl * 16 + ((lane >> 2) ^ (pl & 7))) * 4 + (lane & 3)] = pk;
        }
    };

    // ---- per-batch 64-block barrier: relaxed spin, single fences ----
    auto bbar = [&](unsigned int target) {
        __syncthreads();                      // vmcnt(0): Vb stores complete
        if (tid == 0) {
            unsigned int* c = &P.ctr[batch << 5];
            __builtin_amdgcn_fence(__ATOMIC_RELEASE, "agent");
            __hip_atomic_fetch_add(c, 1u, __ATOMIC_RELAXED,
                                   __HIP_MEMORY_SCOPE_AGENT);
            unsigned int spins = 0;
            while (__hip_atomic_load(c, __ATOMIC_RELAXED,
                                     __HIP_MEMORY_SCOPE_AGENT) < target
                   && spins < 4000000u) {
                ++spins;
                __builtin_amdgcn_s_sleep(2);
            }
            __builtin_amdgcn_fence(__ATOMIC_ACQUIRE, "agent");
        }
        __syncthreads();
    };

    // ---- the network ----
    ffn_body(0, false);
    vfr_body(0, P.Vb0);
    bbar(64);
    te_body(0, P.Vb0);
    __syncthreads();
    ffn_body(1, false);
    vfr_body(1, P.Vb1);
    bbar(128);
    te_body(1, P.Vb1);
    __syncthreads();
    ffn_body(2, true);
}

// ---------------- launch ----------------
extern "C" void kernel_launch(void* const* d_in, const int* in_sizes, int n_in,
                              void* d_out, int out_size, void* d_ws, size_t ws_size,
                              hipStream_t stream)
{
    Params2 p;
    p.x_in = (const float*)d_in[0];
    p.knn  = (const int*)d_in[1];
    const float* w1  = (const float*)d_in[2];
    const float* b1  = (const float*)d_in[3];
    const float* w2  = (const float*)d_in[4];
    const float* b2  = (const float*)d_in[5];
    const float* g0  = (const float*)d_in[6];
    const float* be0 = (const float*)d_in[7];
    const float* m0p = (const float*)d_in[8];
    const float* v0p = (const float*)d_in[9];
    const float* vw  = (const float*)d_in[10];
    const float* vbp = (const float*)d_in[11];
    const float* vgp = (const float*)d_in[12];
    const float* vbe = (const float*)d_in[13];
    const float* vmp = (const float*)d_in[14];
    const float* vvp = (const float*)d_in[15];
    const float* fw1 = (const float*)d_in[16];
    const float* fb1 = (const float*)d_in[17];
    const float* fw2 = (const float*)d_in[18];
    const float* fb2 = (const float*)d_in[19];
    const float* fg  = (const float*)d_in[20];
    const float* fbe = (const float*)d_in[21];
    const float* fm  = (const float*)d_in[22];
    const float* fv  = (const float*)d_in[23];

    p.w1s[0] = w1;  p.w1s[1] = fw1; p.w1s[2] = fw1 + 65536;
    p.w2s[0] = w2;  p.w2s[1] = fw2; p.w2s[2] = fw2 + 65536;
    p.vws[0] = vw;  p.vws[1] = vw + 16384;
    p.b1s[0] = b1;  p.b1s[1] = fb1; p.b1s[2] = fb1 + 512;
    p.b2s[0] = b2;  p.b2s[1] = fb2; p.b2s[2] = fb2 + 128;
    p.gs[0]  = g0;  p.gs[1]  = fg;  p.gs[2]  = fg + 128;
    p.bes[0] = be0; p.bes[1] = fbe; p.bes[2] = fbe + 128;
    p.ms[0]  = m0p; p.ms[1]  = fm;  p.ms[2]  = fm + 128;
    p.vvs[0] = v0p; p.vvs[1] = fv;  p.vvs[2] = fv + 128;
    p.vbb[0] = vbp; p.vbb[1] = vbp + 128;
    p.vgg[0] = vgp; p.vgg[1] = vgp + 128;
    p.vbt[0] = vbe; p.vbt[1] = vbe + 128;
    p.vmm[0] = vmp; p.vmm[1] = vmp + 128;
    p.vva[0] = vvp; p.vva[1] = vvp + 128;

    char* ws = (char*)d_ws;
    p.Vb0 = (unsigned short*)ws;                           // 8 MiB
    p.Vb1 = (unsigned short*)(ws + (size_t)(8 << 20));     // 8 MiB
    unsigned short* u = (unsigned short*)(ws + (size_t)(16 << 20));
    for (int i = 0; i < 3; ++i) p.W1P[i] = u + i * 65536;
    for (int i = 0; i < 3; ++i) p.W2P[i] = u + 196608 + i * 65536;
    for (int i = 0; i < 2; ++i) p.VTP[i] = u + 393216 + i * 16384;
    p.ctr = (unsigned int*)(ws + (size_t)(17 << 20));      // 512 padded words
    p.xf  = (float*)d_out;

    pack2<<<dim3(210), 256, 0, stream>>>(p);
    fused<<<dim3(512), dim3(512), 0, stream>>>(p);
}

// Round 6
// 183.050 us; speedup vs baseline: 2.3372x; 1.5260x over previous
//
#include <hip/hip_runtime.h>
#include <hip/hip_bf16.h>
#include <stdint.h>

typedef __attribute__((ext_vector_type(8))) __bf16 bf16x8;
typedef __attribute__((ext_vector_type(4))) float floatx4;

#define EPS 1e-5f

__device__ __forceinline__ unsigned short f2bf(float f) {
    union { float f; unsigned int u; } x; x.f = f;
    unsigned int r = x.u + 0x7fffu + ((x.u >> 16) & 1u);
    return (unsigned short)(r >> 16);
}

__device__ __forceinline__ float bf2f(unsigned int u) {
    union { unsigned int u; float f; } x; x.u = u << 16; return x.f;
}

struct Params {
    const float* x_in;
    const int*   knn;
    const float* w1s[3];   // [128][512]
    const float* w2s[3];   // [512][128]
    const float* vws[2];   // [128][128]
    unsigned short* W1P[3];
    unsigned short* W2P[3];
    unsigned short* VTP[2];
    const float* b1s[3];
    const float* b2s[3];
    const float* gs[3];
    const float* bes[3];
    const float* ms[3];
    const float* vvs[3];
    const float* vbb[2];
    const float* vgg[2];
    const float* vbt[2];
    const float* vmm[2];
    const float* vva[2];
    float* xf;
};

// ---------------- pack weights, DEST-major (coalesced uint4 stores) --------
// Validated in R3-R5 (all passed). Fragment layout (consumer side):
// W1P short-addr d = hf*16384 + w*2048 + ks*512 + q*128 + ln*8 + j
//   holds W1[k=32ks+8q+j][h=128hf+16w+ln]   (src [128][512], idx=k*512+h)
// W2P same d-layout, holds W2[h=128hf+32ks+8q+j][c=16w+ln]  (src idx=h*128+c)
// VTP d = w*2048+ks*512+q*128+ln*8+j, holds Wv[k=32ks+8q+j][c=16w+ln]
// One thread per 8-short fragment -> 16B uint4 store, coalesced; strided
// fp32 source reads are L2-friendly (weights ~1.8 MB total).
__global__ __launch_bounds__(256) void pack2(Params P) {
    const int gtid = blockIdx.x * 256 + threadIdx.x;
    unsigned short v[8];
    if (gtid < 24576) {                       // W1 x3: 3*8192 fragments
        const int t = gtid >> 13;
        const int d = (gtid & 8191) << 3;
        const int hf = d >> 14, w = (d >> 11) & 7, ks = (d >> 9) & 3,
                  q = (d >> 7) & 3, ln = (d >> 3) & 15;
        const float* s1 = P.w1s[t];
        const int hcol = 128 * hf + 16 * w + ln;
        const int kb   = 32 * ks + 8 * q;
#pragma unroll
        for (int j = 0; j < 8; ++j) v[j] = f2bf(s1[(kb + j) * 512 + hcol]);
        uint4 pk;
        pk.x = v[0] | ((unsigned)v[1] << 16); pk.y = v[2] | ((unsigned)v[3] << 16);
        pk.z = v[4] | ((unsigned)v[5] << 16); pk.w = v[6] | ((unsigned)v[7] << 16);
        *(uint4*)&P.W1P[t][d] = pk;
    } else if (gtid < 49152) {                // W2 x3: 3*8192 fragments
        const int g = gtid - 24576;
        const int t = g >> 13;
        const int d = (g & 8191) << 3;
        const int hf = d >> 14, w = (d >> 11) & 7, ks = (d >> 9) & 3,
                  q = (d >> 7) & 3, ln = (d >> 3) & 15;
        const float* s2 = P.w2s[t];
        const int col = 16 * w + ln;
        const int hb  = 128 * hf + 32 * ks + 8 * q;
#pragma unroll
        for (int j = 0; j < 8; ++j) v[j] = f2bf(s2[(hb + j) * 128 + col]);
        uint4 pk;
        pk.x = v[0] | ((unsigned)v[1] << 16); pk.y = v[2] | ((unsigned)v[3] << 16);
        pk.z = v[4] | ((unsigned)v[5] << 16); pk.w = v[6] | ((unsigned)v[7] << 16);
        *(uint4*)&P.W2P[t][d] = pk;
    } else if (gtid < 53248) {                // VT x2: 2*2048 fragments
        const int g = gtid - 49152;
        const int t = g >> 11;
        const int d = (g & 2047) << 3;
        const int w = (d >> 11) & 7, ks = (d >> 9) & 3,
                  q = (d >> 7) & 3, ln = (d >> 3) & 15;
        const float* sv = P.vws[t];
        const int col = 16 * w + ln;
        const int kb  = 32 * ks + 8 * q;
#pragma unroll
        for (int j = 0; j < 8; ++j) v[j] = f2bf(sv[(kb + j) * 128 + col]);
        uint4 pk;
        pk.x = v[0] | ((unsigned)v[1] << 16); pk.y = v[2] | ((unsigned)v[3] << 16);
        pk.z = v[4] | ((unsigned)v[5] << 16); pk.w = v[6] | ((unsigned)v[7] << 16);
        *(uint4*)&P.VTP[t][d] = pk;
    }
}

// ---------------- fused stage kernel (512 thr = 8 waves, 64 points) --------
// PROVEN R0 structure (184-186 us wall). LDS 64 KB: xt (bf16 x tile, 16K)
// + xf32 (fp32 post-edge x, 32K) + ht2 (one 128-hid slice, 16K).
// Phases: [LOADX] x_in -> xf32+xt | [TE] edge: xf32,xt = xf + BN(edgemax)
//         FFN (hidden-split x4, acc2 accumulated across slices)
//         epilogue2: xf = xf32 + BN(ffn); xt=bf16 | [TV] VFR: VbOut
// XCD swizzle: bid = (phys&7)*64 + phys>>3  => XCD i works on batch i only.
// NOTE (R2-R5 fused-kernel arc, reverted): single-kernel fusion with
// per-batch spin barriers ran 178 us for the SAME work these 3 stages do
// in ~95 us — intra-kernel global barriers (skew + coherence-point polls +
// acquire fences) cost more than the 67 MB xf round-trip they eliminate.
template <int LOADX, int TE, int TF, int TV>
__global__ __launch_bounds__(512, 4)
void stage(Params P, const float* __restrict__ xold_g,
           const unsigned short* __restrict__ VbIn,
           unsigned short* __restrict__ VbOut)
{
    __shared__ __align__(16) unsigned short xt[8192];   // 16 KB
    __shared__ __align__(16) float xf32[8192];          // 32 KB
    __shared__ __align__(16) uint2 ht2[2048];           // 16 KB
    const int tid  = threadIdx.x;
    const int lane = tid & 63;
    const int w    = tid >> 6;       // wave 0..7
    const int q    = lane >> 4;
    const int ln   = lane & 15;
    const int sw   = ln & 7;
    const int phys = blockIdx.x;
    const int bid  = (phys & 7) * 64 + (phys >> 3);   // XCD-local batches
    const int p0   = bid << 6;
    const floatx4 zero = {0.f, 0.f, 0.f, 0.f};

    if constexpr (LOADX) {
        const int r = tid >> 3, seg = tid & 7;
        const float4* src = (const float4*)(xold_g + (size_t)(p0 + r) * 128 + seg * 16);
        float4* dstf = (float4*)&xf32[r * 128 + seg * 16];
#pragma unroll
        for (int i = 0; i < 2; ++i) {
            float4 a = src[2 * i];
            float4 b = src[2 * i + 1];
            dstf[2 * i]     = a;
            dstf[2 * i + 1] = b;
            int kq = seg * 2 + i;
            uint4 pk;
            pk.x = (unsigned int)f2bf(a.x) | ((unsigned int)f2bf(a.y) << 16);
            pk.y = (unsigned int)f2bf(a.z) | ((unsigned int)f2bf(a.w) << 16);
            pk.z = (unsigned int)f2bf(b.x) | ((unsigned int)f2bf(b.y) << 16);
            pk.w = (unsigned int)f2bf(b.z) | ((unsigned int)f2bf(b.w) << 16);
            *(uint4*)&xt[(r * 16 + (kq ^ (r & 7))) * 8] = pk;
        }
    }

    if constexpr (TE >= 0) {
        const int c0 = lane << 1;
        float2 gv = *(const float2*)(P.vgg[TE] + c0);
        float2 bv = *(const float2*)(P.vbt[TE] + c0);
        float2 mv = *(const float2*)(P.vmm[TE] + c0);
        float2 vv = *(const float2*)(P.vva[TE] + c0);
        const float sc0 = gv.x * rsqrtf(vv.x + EPS);
        const float sc1 = gv.y * rsqrtf(vv.y + EPS);
#pragma unroll
        for (int it = 0; it < 8; ++it) {
            const int pl = it * 8 + w;
            const int p  = p0 + pl;
            const int b  = p >> 12;
            const size_t rowoff = (size_t)p * 128 + c0;
            unsigned int su = *(const unsigned int*)(VbIn + rowoff);
            const int4* kp4 = (const int4*)(P.knn + (size_t)p * 16);
            int4 ka = kp4[0], kb = kp4[1], kc = kp4[2], kd = kp4[3];
            const unsigned short* vbase = VbIn + (((size_t)b << 12) << 7) + c0;
            float m0 = -3.4e38f, m1 = -3.4e38f;
            unsigned int u;
#define GATH(IDX) u = *(const unsigned int*)(vbase + ((size_t)(IDX) << 7)); \
            m0 = fmaxf(m0, bf2f(u & 0xffffu)); m1 = fmaxf(m1, bf2f(u >> 16));
            GATH(ka.x) GATH(ka.y) GATH(ka.z) GATH(ka.w)
            GATH(kb.x) GATH(kb.y) GATH(kb.z) GATH(kb.w)
            GATH(kc.x) GATH(kc.y) GATH(kc.z) GATH(kc.w)
            GATH(kd.x) GATH(kd.y) GATH(kd.z) GATH(kd.w)
#undef GATH
            float s0 = bf2f(su & 0xffffu), s1 = bf2f(su >> 16);
            float y0 = (m0 - s0 - mv.x) * sc0 + bv.x;
            float y1 = (m1 - s1 - mv.y) * sc1 + bv.y;
            float2 xv = *(const float2*)(xold_g + rowoff);
            float xn0 = xv.x + y0, xn1 = xv.y + y1;
            *(float2*)&xf32[pl * 128 + c0] = make_float2(xn0, xn1);
            unsigned int pk = (unsigned int)f2bf(xn0) | ((unsigned int)f2bf(xn1) << 16);
            ((unsigned int*)xt)[(pl * 16 + ((lane >> 2) ^ (pl & 7))) * 4 + (lane & 3)] = pk;
        }
    }
    __syncthreads();

    // ---------------- FFN, hidden-split x4 ----------------
    floatx4 acc2[4];
#pragma unroll
    for (int i = 0; i < 4; ++i) acc2[i] = zero;

    const unsigned short* W1 = P.W1P[TF];
    const unsigned short* W2 = P.W2P[TF];
    const float* b1 = P.b1s[TF];

#pragma unroll
    for (int hf = 0; hf < 4; ++hf) {
        // GEMM1: h^T slice (M=128 hid, N=64 pts, K=128); wave w: hid 16w..16w+15
        floatx4 acc1[4];
#pragma unroll
        for (int i = 0; i < 4; ++i) acc1[i] = zero;
        const unsigned short* a1 = W1 + hf * 16384 + w * 2048 + q * 128 + ln * 8;
#pragma unroll
        for (int ks = 0; ks < 4; ++ks) {
            bf16x8 af = *(const bf16x8*)(a1 + ks * 512);
#pragma unroll
            for (int nt = 0; nt < 4; ++nt) {
                bf16x8 bfr = *(const bf16x8*)&xt[((16 * nt + ln) * 16 + ((4 * ks + q) ^ sw)) * 8];
                acc1[nt] = __builtin_amdgcn_mfma_f32_16x16x32_bf16(af, bfr, acc1[nt], 0, 0, 0);
            }
        }
        // epilogue1: +b1, relu, pack 4 consecutive hid -> ht
        {
            const int hid0 = 16 * w + 4 * q;          // within this 128-slice
            const int ghid = 128 * hf + hid0;
            const float bv0 = b1[ghid + 0], bv1 = b1[ghid + 1];
            const float bv2 = b1[ghid + 2], bv3 = b1[ghid + 3];
            const int c16  = hid0 >> 3;
            const int half = q & 1;
#pragma unroll
            for (int nt = 0; nt < 4; ++nt) {
                const int pt = 16 * nt + ln;
                float v0 = acc1[nt][0] + bv0; v0 = v0 > 0.f ? v0 : 0.f;
                float v1 = acc1[nt][1] + bv1; v1 = v1 > 0.f ? v1 : 0.f;
                float v2 = acc1[nt][2] + bv2; v2 = v2 > 0.f ? v2 : 0.f;
                float v3 = acc1[nt][3] + bv3; v3 = v3 > 0.f ? v3 : 0.f;
                uint2 pk;
                pk.x = (unsigned int)f2bf(v0) | ((unsigned int)f2bf(v1) << 16);
                pk.y = (unsigned int)f2bf(v2) | ((unsigned int)f2bf(v3) << 16);
                ht2[(pt * 16 + (c16 ^ (pt & 7))) * 2 + half] = pk;
            }
        }
        __syncthreads();
        // GEMM2: y += h_slice @ W2_slice (M=64 pts, N=128 ch, K=128); wave w: ch 16w..
        const unsigned short* b2b = W2 + hf * 16384 + w * 2048 + q * 128 + ln * 8;
#pragma unroll
        for (int ks = 0; ks < 4; ++ks) {
            bf16x8 bw = *(const bf16x8*)(b2b + ks * 512);
#pragma unroll
            for (int mt = 0; mt < 4; ++mt) {
                bf16x8 ah = *(const bf16x8*)&ht2[((16 * mt + ln) * 16 + ((4 * ks + q) ^ sw)) * 2];
                acc2[mt] = __builtin_amdgcn_mfma_f32_16x16x32_bf16(ah, bw, acc2[mt], 0, 0, 0);
            }
        }
        __syncthreads();
    }

    // epilogue2: +b2, BN, residual (fp32 base from LDS), write xf (+xt)
    {
        const float* b2   = P.b2s[TF];
        const float* gam  = P.gs[TF];
        const float* bet  = P.bes[TF];
        const float* mean = P.ms[TF];
        const float* var  = P.vvs[TF];
        const int c = 16 * w + ln;
        const float bia = b2[c];
        const float sc  = gam[c] * rsqrtf(var[c] + EPS);
        const float bb  = bet[c];
        const float mu  = mean[c];
#pragma unroll
        for (int mt = 0; mt < 4; ++mt) {
#pragma unroll
            for (int r = 0; r < 4; ++r) {
                const int rl = 16 * mt + 4 * q + r;
                float v  = acc2[mt][r] + bia;
                float y  = (v - mu) * sc + bb;
                float xn = xf32[rl * 128 + c] + y;
                P.xf[(size_t)(p0 + rl) * 128 + c] = xn;
                if constexpr (TV >= 0)
                    xt[(rl * 16 + ((c >> 3) ^ (rl & 7))) * 8 + (c & 7)] = f2bf(xn);
            }
        }
    }

    // ---------------- VFR linear ----------------
    if constexpr (TV >= 0) {
        __syncthreads();
        const unsigned short* VT = P.VTP[TV];
        const float* vb = P.vbb[TV];
        floatx4 acc[4];
#pragma unroll
        for (int i = 0; i < 4; ++i) acc[i] = zero;
        const unsigned short* bb2 = VT + w * 2048 + q * 128 + ln * 8;
#pragma unroll
        for (int ks = 0; ks < 4; ++ks) {
            bf16x8 bw = *(const bf16x8*)(bb2 + ks * 512);
#pragma unroll
            for (int mt = 0; mt < 4; ++mt) {
                bf16x8 ax = *(const bf16x8*)&xt[((16 * mt + ln) * 16 + ((4 * ks + q) ^ sw)) * 8];
                acc[mt] = __builtin_amdgcn_mfma_f32_16x16x32_bf16(ax, bw, acc[mt], 0, 0, 0);
            }
        }
        const int c = 16 * w + ln;
        const float bia = vb[c];
#pragma unroll
        for (int mt = 0; mt < 4; ++mt)
#pragma unroll
            for (int r = 0; r < 4; ++r)
                VbOut[(size_t)(p0 + 16 * mt + 4 * q + r) * 128 + c] = f2bf(acc[mt][r] + bia);
    }
}

// ---------------- launch ----------------
extern "C" void kernel_launch(void* const* d_in, const int* in_sizes, int n_in,
                              void* d_out, int out_size, void* d_ws, size_t ws_size,
                              hipStream_t stream)
{
    Params p;
    p.x_in = (const float*)d_in[0];
    p.knn  = (const int*)d_in[1];
    const float* w1  = (const float*)d_in[2];
    const float* b1  = (const float*)d_in[3];
    const float* w2  = (const float*)d_in[4];
    const float* b2  = (const float*)d_in[5];
    const float* g0  = (const float*)d_in[6];
    const float* be0 = (const float*)d_in[7];
    const float* m0p = (const float*)d_in[8];
    const float* v0p = (const float*)d_in[9];
    const float* vw  = (const float*)d_in[10];
    const float* vbp = (const float*)d_in[11];
    const float* vgp = (const float*)d_in[12];
    const float* vbe = (const float*)d_in[13];
    const float* vmp = (const float*)d_in[14];
    const float* vvp = (const float*)d_in[15];
    const float* fw1 = (const float*)d_in[16];
    const float* fb1 = (const float*)d_in[17];
    const float* fw2 = (const float*)d_in[18];
    const float* fb2 = (const float*)d_in[19];
    const float* fg  = (const float*)d_in[20];
    const float* fbe = (const float*)d_in[21];
    const float* fm  = (const float*)d_in[22];
    const float* fv  = (const float*)d_in[23];

    p.w1s[0] = w1;  p.w1s[1] = fw1; p.w1s[2] = fw1 + 65536;
    p.w2s[0] = w2;  p.w2s[1] = fw2; p.w2s[2] = fw2 + 65536;
    p.vws[0] = vw;  p.vws[1] = vw + 16384;
    p.b1s[0] = b1;  p.b1s[1] = fb1; p.b1s[2] = fb1 + 512;
    p.b2s[0] = b2;  p.b2s[1] = fb2; p.b2s[2] = fb2 + 128;
    p.gs[0]  = g0;  p.gs[1]  = fg;  p.gs[2]  = fg + 128;
    p.bes[0] = be0; p.bes[1] = fbe; p.bes[2] = fbe + 128;
    p.ms[0]  = m0p; p.ms[1]  = fm;  p.ms[2]  = fm + 128;
    p.vvs[0] = v0p; p.vvs[1] = fv;  p.vvs[2] = fv + 128;
    p.vbb[0] = vbp; p.vbb[1] = vbp + 128;
    p.vgg[0] = vgp; p.vgg[1] = vgp + 128;
    p.vbt[0] = vbe; p.vbt[1] = vbe + 128;
    p.vmm[0] = vmp; p.vmm[1] = vmp + 128;
    p.vva[0] = vvp; p.vva[1] = vvp + 128;

    char* ws = (char*)d_ws;
    unsigned short* Vb0 = (unsigned short*)ws;                          // 8 MiB
    unsigned short* Vb1 = (unsigned short*)(ws + (size_t)(8 << 20));    // 8 MiB
    unsigned short* u   = (unsigned short*)(ws + (size_t)(16 << 20));   // packed weights
    for (int i = 0; i < 3; ++i) p.W1P[i] = u + i * 65536;
    for (int i = 0; i < 3; ++i) p.W2P[i] = u + 196608 + i * 65536;
    for (int i = 0; i < 2; ++i) p.VTP[i] = u + 393216 + i * 16384;
    p.xf = (float*)d_out;

    pack2<<<dim3(208), 256, 0, stream>>>(p);
    stage<1, -1, 0, 0><<<dim3(512), 512, 0, stream>>>(p, p.x_in, nullptr, Vb0);
    stage<0,  0, 1, 1><<<dim3(512), 512, 0, stream>>>(p, p.xf, Vb0, Vb1);
    stage<0,  1, 2, -1><<<dim3(512), 512, 0, stream>>>(p, p.xf, Vb1, nullptr);
}